// Round 7
// baseline (7631.042 us; speedup 1.0000x reference)
//
#include <hip/hip_runtime.h>
#include <hip/hip_bf16.h>
#include <cstddef>

typedef __bf16 bf16_t;
typedef bf16_t bf16x8 __attribute__((ext_vector_type(8)));
typedef bf16_t bf16x4 __attribute__((ext_vector_type(4)));
typedef float  f32x4  __attribute__((ext_vector_type(4)));
typedef unsigned u32x4 __attribute__((ext_vector_type(4)));

#define T_STEPS 256
#define BATCH   32
#define HDIM    1024
#define ZDIM    4096

// ---------------- workspace sizes ----------------
constexpr size_t SZ_HSEQ  = (size_t)8192 * 1024 * 2;       // 16 MiB (hi or lo)
constexpr size_t SZ_CPUB  = (size_t)2 * 32 * 1024 * 4;     // 256 KiB packed c
constexpr size_t SZ_SPUB  = (size_t)2 * 32 * 1024 * 4;     // 256 KiB packed sg
constexpr size_t SZ_PART  = (size_t)2 * 4 * 64 * 16 * 4;   // 32 KiB
constexpr size_t SZ_FLAG  = (size_t)256 * 4 * 64 * 4;      // 256 KiB per layer
constexpr size_t SZ_HST   = (size_t)32 * 1024 * 2;         // 64 KiB (hi or lo)
constexpr size_t SZ_CST   = (size_t)32 * 1024 * 4;         // 128 KiB
constexpr size_t SZ_MU    = 256;
constexpr size_t SZ_TAIL  = SZ_CPUB + SZ_SPUB + SZ_PART + 2*SZ_FLAG + 2*SZ_HST + SZ_CST + SZ_MU;
constexpr int    ZERO_WORDS = (int)(2*SZ_FLAG / 4);

// ---------------- LDS ----------------
constexpr int SLAB_STRIDE = 264;                 // W staging rows (bf16)
constexpr int HL_STRIDE   = 1040;                // h rows (bf16), 2080 B
// post-staging: hl_hi [8][1040] @0, hl_lo @16640, sred[128] @33280, stot[16] @33792
constexpr int SCAN_LDS    = 2 * 64 * SLAB_STRIDE * 2;  // 67584

__global__ void init_zero(unsigned* __restrict__ p, int n) {
    int i = blockIdx.x * blockDim.x + threadIdx.x;
    if (i < n) p[i] = 0u;
}

__device__ __forceinline__ void split_bf16(float v, bf16_t& hi, bf16_t& lo) {
    hi = (bf16_t)v;
    lo = (bf16_t)(v - (float)hi);
}
__device__ __forceinline__ unsigned short bf16_bits(bf16_t f) {
    union { unsigned short u; bf16_t f2; } x; x.f2 = f; return x.u;
}
__device__ __forceinline__ unsigned pack_hl(float v) {
    bf16_t hi, lo; split_bf16(v, hi, lo);
    return ((unsigned)bf16_bits(hi) << 16) | (unsigned)bf16_bits(lo);
}
__device__ __forceinline__ float unpack_hl(unsigned u) {
    union { unsigned u2; float f; } a, b;
    a.u2 = u & 0xffff0000u;
    b.u2 = u << 16;
    return a.f + b.f;
}
__device__ __forceinline__ float tanh_fast(float x) {
    // 1 - 2/(e^{2x}+1); fp32-safe at extremes (exp->inf or 0)
    float e = __expf(2.f * x);
    return 1.f - 2.f * __builtin_amdgcn_rcpf(e + 1.f);
}

// ---------------- input-projection GEMM (split-precision bf16x2) ----------------
// MODE 0: A fp32 with series row-remap (layer0, K=256)
// MODE 1: A pre-split hi/lo bf16 (layer1, K=1024)
template<int KTOT, int MODE>
__global__ __launch_bounds__(256) void gemm_xp(
    const float*  __restrict__ Afp,
    const bf16_t* __restrict__ Ahi,
    const bf16_t* __restrict__ Alo,
    const float*  __restrict__ W,
    const float*  __restrict__ bias,
    float*        __restrict__ xp,
    int t0)
{
    __shared__ bf16_t Ash[64][40], Asl[64][40], Bsh[64][40], Bsl[64][40];
    const int bm = blockIdx.x / (ZDIM/64);
    const int bn = blockIdx.x % (ZDIM/64);
    const int tid  = threadIdx.x;
    const int lane = tid & 63;
    const int w    = tid >> 6;
    const int wm = w >> 1, wn = w & 1;
    const int q   = lane >> 4;
    const int l15 = lane & 15;

    f32x4 acc[2][2] = {};

    const int sm = tid & 63;
    const int sk = (tid >> 6) * 8;
    const int gr = t0*32 + bm*64 + sm;
    const float*  Arow  = nullptr;
    const bf16_t* Ahrow = nullptr;
    const bf16_t* Alrow = nullptr;
    if constexpr (MODE == 0) {
        int tt = gr >> 5, bb = gr & 31;
        Arow = Afp + ((size_t)bb * T_STEPS + tt) * 256;
    } else {
        Ahrow = Ahi + (size_t)gr * HDIM;
        Alrow = Alo + (size_t)gr * HDIM;
    }
    const int gcol = bn*64 + sm;

    for (int k0 = 0; k0 < KTOT; k0 += 32) {
        if constexpr (MODE == 0) {
            f32x4 a0 = *(const f32x4*)(Arow + k0 + sk);
            f32x4 a1 = *(const f32x4*)(Arow + k0 + sk + 4);
            #pragma unroll
            for (int j = 0; j < 4; ++j) {
                split_bf16(a0[j], Ash[sm][sk+j],   Asl[sm][sk+j]);
                split_bf16(a1[j], Ash[sm][sk+4+j], Asl[sm][sk+4+j]);
            }
        } else {
            *(bf16x8*)&Ash[sm][sk] = *(const bf16x8*)(Ahrow + k0 + sk);
            *(bf16x8*)&Asl[sm][sk] = *(const bf16x8*)(Alrow + k0 + sk);
        }
        #pragma unroll
        for (int j = 0; j < 8; ++j) {
            float wv = W[(size_t)(k0 + sk + j) * ZDIM + gcol];
            split_bf16(wv, Bsh[sm][sk+j], Bsl[sm][sk+j]);
        }
        __syncthreads();
        #pragma unroll
        for (int mt = 0; mt < 2; ++mt) {
            #pragma unroll
            for (int nt = 0; nt < 2; ++nt) {
                bf16x8 ah = *(const bf16x8*)&Ash[wm*32 + mt*16 + l15][q*8];
                bf16x8 al = *(const bf16x8*)&Asl[wm*32 + mt*16 + l15][q*8];
                bf16x8 bh = *(const bf16x8*)&Bsh[wn*32 + nt*16 + l15][q*8];
                bf16x8 bl = *(const bf16x8*)&Bsl[wn*32 + nt*16 + l15][q*8];
                acc[mt][nt] = __builtin_amdgcn_mfma_f32_16x16x32_bf16(ah, bh, acc[mt][nt], 0, 0, 0);
                acc[mt][nt] = __builtin_amdgcn_mfma_f32_16x16x32_bf16(al, bh, acc[mt][nt], 0, 0, 0);
                acc[mt][nt] = __builtin_amdgcn_mfma_f32_16x16x32_bf16(ah, bl, acc[mt][nt], 0, 0, 0);
            }
        }
        __syncthreads();
    }
    #pragma unroll
    for (int mt = 0; mt < 2; ++mt) {
        int row = bm*64 + wm*32 + mt*16 + q*4;
        #pragma unroll
        for (int nt = 0; nt < 2; ++nt) {
            int col = bn*64 + wn*32 + nt*16 + l15;
            float bia = bias[col];
            #pragma unroll
            for (int r = 0; r < 4; ++r)
                xp[(size_t)(row + r)*ZDIM + col] = acc[mt][nt][r] + bia;
        }
    }
}

// ---------------- persistent recurrent scan: SINGLE rendezvous, consumer-LN ------
// grid 256 x 256. group gid=blk>>6 owns batches 8*gid..+7; block lid=blk&63 owns
// h-cols H0=lid*16..+15 for the MFMA. W in register hi/lo bf16 A-fragments.
// Per step: MFMA -> gates -> publish c,sg (hi/lo-packed u32) + stat partials ->
// ONE flag+poll -> staging loads (overlap wave0 stats butterfly) -> every block
// computes LN+h for its group's 8 rows with exp-tanh, col-major thread map
// (gamma/beta in 4 regs, conflict-free LDS), packs hi/lo into LDS for next MFMA.
// R6 was two-rendezvous RTT+straggler bound; R5's consumer-LN overheads removed.
__global__ __launch_bounds__(256, 1) void scan_kernel(
    const float* __restrict__ Wh,      // [1024][4096] fp32 recurrent rows
    const float* __restrict__ xp,      // [cT*32][4096] fp32 x-proj (incl bias)
    const float* __restrict__ gamma,
    const float* __restrict__ beta,
    unsigned*    cpubP,                // [2][32][1024] packed c (coherent)
    unsigned*    spubP,                // [2][32][1024] packed sg (coherent)
    float*       part,                 // [2][4][64][16] fp32 (coherent)
    unsigned*    flag,                 // [T][4][64] (zeroed)
    bf16_t*      __restrict__ hseq_hi, // [T*32][1024] or null (layer0)
    bf16_t*      __restrict__ hseq_lo,
    float*       __restrict__ outlast, // [32][1024] or null (layer1)
    bf16_t*      __restrict__ hst_hi,  // [32][1024] chunk-carry
    bf16_t*      __restrict__ hst_lo,
    float*       __restrict__ cstate,  // [32][1024]
    float*       __restrict__ mustate, // [32]
    int t0, int t1)
{
    extern __shared__ char smem[];
    bf16_t* slab_hi = (bf16_t*)smem;                       // W staging
    bf16_t* slab_lo = (bf16_t*)(smem + 64*SLAB_STRIDE*2);
    bf16_t* hl_hi   = (bf16_t*)smem;                       // [8][1040] post-staging
    bf16_t* hl_lo   = (bf16_t*)(smem + 8*HL_STRIDE*2);
    float*  sred    = (float*)(smem + 16*HL_STRIDE*2);     // [4][16][2]
    float*  stot    = sred + 128;                          // [16]

    const int gid = blockIdx.x >> 6;
    const int lid = blockIdx.x & 63;
    const int B0  = gid * 8;
    const int H0  = lid * 16;
    const int tid  = threadIdx.x;
    const int lane = tid & 63;
    const int w    = tid >> 6;
    const int q    = lane >> 4;
    const int l15  = lane & 15;

    // ---- stage recurrent W slice -> registers (hi/lo A-fragments) via LDS slabs
    bf16x8 wf_hi[32], wf_lo[32];
    {
        const int kw   = tid >> 6;
        const int strip= (tid >> 4) & 3;
        const int col  = tid & 15;
        const int gc2  = strip*1024 + H0 + col;
        const int rr_w = col*4 + strip;
        #pragma unroll
        for (int s = 0; s < 4; ++s) {
            for (int j = 0; j < 64; ++j) {
                int kk = j*4 + kw;
                float v = Wh[(size_t)(s*256 + kk)*ZDIM + gc2];
                bf16_t hi, lo; split_bf16(v, hi, lo);
                slab_hi[rr_w*SLAB_STRIDE + kk] = hi;
                slab_lo[rr_w*SLAB_STRIDE + kk] = lo;
            }
            __syncthreads();
            #pragma unroll
            for (int kbl = 0; kbl < 8; ++kbl) {
                wf_hi[s*8+kbl] = *(const bf16x8*)&slab_hi[(16*w + l15)*SLAB_STRIDE + kbl*32 + q*8];
                wf_lo[s*8+kbl] = *(const bf16x8*)&slab_lo[(16*w + l15)*SLAB_STRIDE + kbl*32 + q*8];
            }
            __syncthreads();
        }
    }

    // owner identity (MFMA C map)
    const int  bidx  = l15;
    const bool valid = bidx < 8;
    const int  batch = B0 + bidx;
    const int  hcl   = 4*w + q;
    const int  hcg   = H0 + hcl;
    const size_t xpbase = (size_t)batch * ZDIM + (size_t)H0 + hcl;
    const int hrow  = (l15 < 8) ? l15 : 7;

    // staging identity: thread owns cols cb..cb+3 for all 8 group rows
    const int cb = tid * 4;
    const f32x4 g_s = *(const f32x4*)&gamma[cb];
    const f32x4 b_s = *(const f32x4*)&beta[cb];

    float c = 0.f, mu_pub = 0.f;
    float mu_row[8] = {0.f,0.f,0.f,0.f,0.f,0.f,0.f,0.f};
    if (t0 > 0) {
        if (valid) {
            c = cstate[(size_t)batch*HDIM + hcg];
            mu_pub = mustate[batch];
        }
        #pragma unroll
        for (int r = 0; r < 8; ++r) {
            mu_row[r] = mustate[B0 + r];
            *(bf16x4*)&hl_hi[r*HL_STRIDE + cb] = *(const bf16x4*)&hst_hi[(size_t)(B0+r)*HDIM + cb];
            *(bf16x4*)&hl_lo[r*HL_STRIDE + cb] = *(const bf16x4*)&hst_lo[(size_t)(B0+r)*HDIM + cb];
        }
    }
    __syncthreads();

    // preload xp for first step
    float xpv[4] = {0.f, 0.f, 0.f, 0.f};
    if (valid) {
        const float* xpt = xp + xpbase;
        #pragma unroll
        for (int r = 0; r < 4; ++r) xpv[r] = xpt[(size_t)r * 1024];
    }

    #pragma unroll 1
    for (int t = t0; t < t1; ++t) {
        f32x4 acc_hh = {0.f,0.f,0.f,0.f}, acc_lh = acc_hh, acc_hl = acc_hh;
        if (t > 0) {
            const bf16_t* Bh = hl_hi + (size_t)hrow * HL_STRIDE + q*8;
            const bf16_t* Bl = hl_lo + (size_t)hrow * HL_STRIDE + q*8;
            #pragma unroll
            for (int kb = 0; kb < 32; ++kb) {
                bf16x8 bh = *(const bf16x8*)(Bh + kb*32);
                bf16x8 bv = *(const bf16x8*)(Bl + kb*32);
                acc_hh = __builtin_amdgcn_mfma_f32_16x16x32_bf16(wf_hi[kb], bh, acc_hh, 0, 0, 0);
                acc_lh = __builtin_amdgcn_mfma_f32_16x16x32_bf16(wf_lo[kb], bh, acc_lh, 0, 0, 0);
                acc_hl = __builtin_amdgcn_mfma_f32_16x16x32_bf16(wf_hi[kb], bv, acc_hl, 0, 0, 0);
            }
        }
        float z[4];
        #pragma unroll
        for (int r = 0; r < 4; ++r)
            z[r] = ((acc_lh[r] + acc_hl[r]) + acc_hh[r]) + xpv[r];
        float zi = fminf(fmaxf(z[0], -6.f), 3.f);
        float zf = fminf(fmaxf(z[1], -6.f), 3.f);
        float ig = __expf(zi);
        float fg = __expf(zf);
        float cand = tanh_fast(z[2]);
        float sg = 1.f / (1.f + __expf(-z[3]));
        c = fg * c + ig * cand;

        // prefetch next step's xp (off critical path)
        if (valid && t+1 < t1) {
            const float* xpt = xp + (size_t)(t+1 - t0) * (BATCH*ZDIM) + xpbase;
            #pragma unroll
            for (int r = 0; r < 4; ++r) xpv[r] = xpt[(size_t)r * 1024];
        }

        const int par = t & 1;
        // ---- publish c, sg (hi/lo packed u32, coherent)
        if (valid) {
            *(volatile unsigned*)(cpubP + ((size_t)par*32 + batch)*HDIM + hcg) = pack_hl(c);
            *(volatile unsigned*)(spubP + ((size_t)par*32 + batch)*HDIM + hcg) = pack_hl(sg);
        }
        // wave stat partials (shifted by mu_pub)
        float dm = valid ? (c - mu_pub) : 0.f;
        float s1 = dm, s2 = dm * dm;
        s1 += __shfl_xor(s1, 16); s2 += __shfl_xor(s2, 16);
        s1 += __shfl_xor(s1, 32); s2 += __shfl_xor(s2, 32);
        if (q == 0 && l15 < 8) { sred[(w*16 + l15)*2] = s1; sred[(w*16 + l15)*2 + 1] = s2; }
        __syncthreads();   // B1: sred ready; ALL waves' c/sg stores drained (vmcnt)

        // ---- single rendezvous
        unsigned* fl = flag + ((size_t)t*4 + gid)*64;
        if (w == 0) {
            if (lane < 16) {
                int b = lane >> 1, comp = lane & 1;
                float P = sred[(0*16+b)*2+comp] + sred[(1*16+b)*2+comp]
                        + sred[(2*16+b)*2+comp] + sred[(3*16+b)*2+comp];
                *(volatile float*)(part + (((size_t)par*4 + gid)*64 + lid)*16 + lane) = P;
            }
            asm volatile("s_waitcnt vmcnt(0)" ::: "memory");
            if (lane == 0)
                __hip_atomic_store(&fl[lid], 1u, __ATOMIC_RELAXED, __HIP_MEMORY_SCOPE_AGENT);
            for (;;) {
                unsigned f = __hip_atomic_load(&fl[lane], __ATOMIC_RELAXED, __HIP_MEMORY_SCOPE_AGENT);
                if (__ballot(f != 0u) == ~0ull) break;
                __builtin_amdgcn_s_sleep(1);
            }
        }
        __syncthreads();   // Ba: all threads may now read published data

        // staging loads issue first (latency overlaps wave0's butterfly)
        u32x4 uc[8], us[8];
        #pragma unroll
        for (int r = 0; r < 8; ++r) {
            uc[r] = *(volatile const u32x4*)(cpubP + ((size_t)par*32 + B0 + r)*HDIM + cb);
            us[r] = *(volatile const u32x4*)(spubP + ((size_t)par*32 + B0 + r)*HDIM + cb);
        }
        if (w == 0) {
            volatile const f32x4* pb = (volatile const f32x4*)(part + (((size_t)par*4 + gid)*64 + lane)*16);
            f32x4 p0 = pb[0], p1 = pb[1], p2 = pb[2], p3 = pb[3];
            #pragma unroll
            for (int m = 1; m < 64; m <<= 1) {
                #pragma unroll
                for (int e = 0; e < 4; ++e) {
                    p0[e] += __shfl_xor(p0[e], m);
                    p1[e] += __shfl_xor(p1[e], m);
                    p2[e] += __shfl_xor(p2[e], m);
                    p3[e] += __shfl_xor(p3[e], m);
                }
            }
            if (lane == 0) {
                *(f32x4*)&stot[0]  = p0;
                *(f32x4*)&stot[4]  = p1;
                *(f32x4*)&stot[8]  = p2;
                *(f32x4*)&stot[12] = p3;
            }
        }
        __syncthreads();   // Bb: stot ready

        if (valid) mu_pub += stot[2*bidx] * (1.f/1024.f);

        // ---- consumer LN + h for all 8 rows (exp-tanh, reg gamma/beta)
        const bool l0 = (hseq_hi != nullptr);
        const bool carry = (t == t1-1) && (t1 < T_STEPS);
        #pragma unroll
        for (int r = 0; r < 8; ++r) {
            float dmu = stot[2*r] * (1.f/1024.f);
            float mu  = mu_row[r] + dmu;
            float var = stot[2*r+1] * (1.f/1024.f) - dmu*dmu;
            float rsig = rsqrtf(var + 1e-5f);
            mu_row[r] = mu;
            bf16x4 bh, blv;
            f32x4 hv4;
            #pragma unroll
            for (int e = 0; e < 4; ++e) {
                float cv  = unpack_hl(uc[r][e]);
                float sgv = unpack_hl(us[r][e]);
                float ln  = (cv - mu) * rsig * g_s[e] + b_s[e];
                float h   = sgv * tanh_fast(ln);
                hv4[e] = h;
                bf16_t hi, lo; split_bf16(h, hi, lo);
                bh[e] = hi; blv[e] = lo;
            }
            *(bf16x4*)&hl_hi[r*HL_STRIDE + cb] = bh;
            *(bf16x4*)&hl_lo[r*HL_STRIDE + cb] = blv;
            if (l0 && lid == r) {
                *(bf16x4*)&hseq_hi[((size_t)t*32 + B0 + r)*HDIM + cb] = bh;
                *(bf16x4*)&hseq_lo[((size_t)t*32 + B0 + r)*HDIM + cb] = blv;
            }
            if (carry && lid == r) {
                *(bf16x4*)&hst_hi[(size_t)(B0+r)*HDIM + cb] = bh;
                *(bf16x4*)&hst_lo[(size_t)(B0+r)*HDIM + cb] = blv;
            }
            if (outlast && t == T_STEPS-1 && lid == r)
                *(f32x4*)&outlast[(size_t)(B0+r)*HDIM + cb] = hv4;
        }
        __syncthreads();   // B3: hl ready for next step's MFMA
    }

    // chunk-carry state
    if (t1 < T_STEPS) {
        if (valid) cstate[(size_t)batch*HDIM + hcg] = c;
        if (lid == 0 && tid == 0) {
            #pragma unroll
            for (int r = 0; r < 8; ++r) mustate[B0 + r] = mu_row[r];
        }
    }
}

extern "C" void kernel_launch(void* const* d_in, const int* in_sizes, int n_in,
                              void* d_out, int out_size, void* d_ws, size_t ws_size,
                              hipStream_t stream) {
    (void)in_sizes; (void)n_in;
    const float* series = (const float*)d_in[0];
    const float* W0  = (const float*)d_in[1];
    const float* b0  = (const float*)d_in[2];
    const float* g0  = (const float*)d_in[3];
    const float* be0 = (const float*)d_in[4];
    const float* W1  = (const float*)d_in[5];
    const float* b1  = (const float*)d_in[6];
    const float* g1  = (const float*)d_in[7];
    const float* be1 = (const float*)d_in[8];
    float* out = (float*)d_out;
    unsigned char* ws = (unsigned char*)d_ws;

    int cT = 0;
    const int cands[4] = {256, 128, 64, 32};
    for (int i = 0; i < 4; ++i) {
        size_t need = (size_t)cands[i]*32*ZDIM*4 + 2*SZ_HSEQ + SZ_TAIL;
        if (need <= ws_size) { cT = cands[i]; break; }
    }
    if (cT == 0) {
        (void)hipMemsetAsync(d_out, 0, (size_t)out_size * sizeof(float), stream);
        return;
    }
    const size_t sz_xp = (size_t)cT*32*ZDIM*4;
    unsigned char* p = ws;
    float*    xp      = (float*)p;    p += sz_xp;
    bf16_t*   hseq_hi = (bf16_t*)p;   p += SZ_HSEQ;
    bf16_t*   hseq_lo = (bf16_t*)p;   p += SZ_HSEQ;
    unsigned* cpubP   = (unsigned*)p; p += SZ_CPUB;
    unsigned* spubP   = (unsigned*)p; p += SZ_SPUB;
    float*    part    = (float*)p;    p += SZ_PART;
    unsigned* flag0   = (unsigned*)p; p += SZ_FLAG;   // 2 contiguous flag arrays
    unsigned* flag1   = (unsigned*)p; p += SZ_FLAG;
    bf16_t*   hst_hi  = (bf16_t*)p;   p += SZ_HST;
    bf16_t*   hst_lo  = (bf16_t*)p;   p += SZ_HST;
    float*    cstate  = (float*)p;    p += SZ_CST;
    float*    mustate = (float*)p;

    (void)hipFuncSetAttribute((const void*)scan_kernel,
                              hipFuncAttributeMaxDynamicSharedMemorySize, SCAN_LDS);

    init_zero<<<(ZERO_WORDS + 255)/256, 256, 0, stream>>>(flag0, ZERO_WORDS);

    const int nch = T_STEPS / cT;
    const int gemm_grid = (cT*32/64) * (ZDIM/64);

    // ---- layer 0 ----
    for (int ci = 0; ci < nch; ++ci) {
        int t0 = ci*cT, t1 = t0 + cT;
        gemm_xp<256, 0><<<gemm_grid, 256, 0, stream>>>(
            series, nullptr, nullptr, W0, b0, xp, t0);
        scan_kernel<<<256, 256, SCAN_LDS, stream>>>(
            W0 + (size_t)256*ZDIM, xp, g0, be0, cpubP, spubP, part, flag0,
            hseq_hi, hseq_lo, nullptr, hst_hi, hst_lo, cstate, mustate, t0, t1);
    }
    // ---- layer 1 ----
    for (int ci = 0; ci < nch; ++ci) {
        int t0 = ci*cT, t1 = t0 + cT;
        gemm_xp<1024, 1><<<gemm_grid, 256, 0, stream>>>(
            nullptr, hseq_hi, hseq_lo, W1, b1, xp, t0);
        scan_kernel<<<256, 256, SCAN_LDS, stream>>>(
            W1 + (size_t)1024*ZDIM, xp, g1, be1, cpubP, spubP, part, flag1,
            nullptr, nullptr, out, hst_hi, hst_lo, cstate, mustate, t0, t1);
    }
}

// Round 8
// 6228.878 us; speedup vs baseline: 1.2251x; 1.2251x over previous
//
#include <hip/hip_runtime.h>
#include <hip/hip_bf16.h>
#include <cstddef>

typedef __bf16 bf16_t;
typedef bf16_t bf16x8 __attribute__((ext_vector_type(8)));
typedef bf16_t bf16x4 __attribute__((ext_vector_type(4)));
typedef float  f32x4  __attribute__((ext_vector_type(4)));
typedef unsigned u32x4 __attribute__((ext_vector_type(4)));
typedef unsigned u32x2 __attribute__((ext_vector_type(2)));

#define T_STEPS 256
#define BATCH   32
#define HDIM    1024
#define ZDIM    4096

// ---------------- workspace sizes ----------------
constexpr size_t SZ_HSEQ  = (size_t)8192 * 1024 * 2;       // 16 MiB (hi or lo)
constexpr size_t SZ_CSG   = (size_t)2 * 32 * 1024 * 2 * 4; // 512 KiB packed (c,sg) pairs
constexpr size_t SZ_FLAG  = (size_t)256 * 4 * 64 * 4;      // 256 KiB per layer
constexpr size_t SZ_HST   = (size_t)32 * 1024 * 2;         // 64 KiB (hi or lo)
constexpr size_t SZ_CST   = (size_t)32 * 1024 * 4;         // 128 KiB
constexpr size_t SZ_MU    = 256;
constexpr size_t SZ_TAIL  = SZ_CSG + 2*SZ_FLAG + 2*SZ_HST + SZ_CST + SZ_MU;
constexpr int    ZERO_WORDS = (int)(2*SZ_FLAG / 4);

// ---------------- LDS ----------------
constexpr int SLAB_STRIDE = 264;                 // W staging rows (bf16)
constexpr int HL_STRIDE   = 1040;                // h rows (bf16), 2080 B
// post-staging: hl_hi [8][1040] @0, hl_lo @16640, sredw[4][8][2] @33280
constexpr int SCAN_LDS    = 2 * 64 * SLAB_STRIDE * 2;  // 67584

__global__ void init_zero(unsigned* __restrict__ p, int n) {
    int i = blockIdx.x * blockDim.x + threadIdx.x;
    if (i < n) p[i] = 0u;
}

__device__ __forceinline__ void split_bf16(float v, bf16_t& hi, bf16_t& lo) {
    hi = (bf16_t)v;
    lo = (bf16_t)(v - (float)hi);
}
__device__ __forceinline__ unsigned short bf16_bits(bf16_t f) {
    union { unsigned short u; bf16_t f2; } x; x.f2 = f; return x.u;
}
__device__ __forceinline__ unsigned pack_hl(float v) {
    bf16_t hi, lo; split_bf16(v, hi, lo);
    return ((unsigned)bf16_bits(hi) << 16) | (unsigned)bf16_bits(lo);
}
__device__ __forceinline__ float unpack_hl(unsigned u) {
    union { unsigned u2; float f; } a, b;
    a.u2 = u & 0xffff0000u;
    b.u2 = u << 16;
    return a.f + b.f;
}
__device__ __forceinline__ float tanh_fast(float x) {
    float e = __expf(2.f * x);
    return 1.f - 2.f * __builtin_amdgcn_rcpf(e + 1.f);
}
// light barriers: raw s_barrier, draining only what the handoff needs
__device__ __forceinline__ void bar_raw() {
    asm volatile("" ::: "memory");
    __builtin_amdgcn_s_barrier();
    asm volatile("" ::: "memory");
}
__device__ __forceinline__ void bar_lds() {
    asm volatile("s_waitcnt lgkmcnt(0)" ::: "memory");
    __builtin_amdgcn_s_barrier();
    asm volatile("" ::: "memory");
}

// ---------------- input-projection GEMM (split-precision bf16x2) ----------------
// MODE 0: A fp32 with series row-remap (layer0, K=256)
// MODE 1: A pre-split hi/lo bf16 (layer1, K=1024)
template<int KTOT, int MODE>
__global__ __launch_bounds__(256) void gemm_xp(
    const float*  __restrict__ Afp,
    const bf16_t* __restrict__ Ahi,
    const bf16_t* __restrict__ Alo,
    const float*  __restrict__ W,
    const float*  __restrict__ bias,
    float*        __restrict__ xp,
    int t0)
{
    __shared__ bf16_t Ash[64][40], Asl[64][40], Bsh[64][40], Bsl[64][40];
    const int bm = blockIdx.x / (ZDIM/64);
    const int bn = blockIdx.x % (ZDIM/64);
    const int tid  = threadIdx.x;
    const int lane = tid & 63;
    const int w    = tid >> 6;
    const int wm = w >> 1, wn = w & 1;
    const int q   = lane >> 4;
    const int l15 = lane & 15;

    f32x4 acc[2][2] = {};

    const int sm = tid & 63;
    const int sk = (tid >> 6) * 8;
    const int gr = t0*32 + bm*64 + sm;
    const float*  Arow  = nullptr;
    const bf16_t* Ahrow = nullptr;
    const bf16_t* Alrow = nullptr;
    if constexpr (MODE == 0) {
        int tt = gr >> 5, bb = gr & 31;
        Arow = Afp + ((size_t)bb * T_STEPS + tt) * 256;
    } else {
        Ahrow = Ahi + (size_t)gr * HDIM;
        Alrow = Alo + (size_t)gr * HDIM;
    }
    const int gcol = bn*64 + sm;

    for (int k0 = 0; k0 < KTOT; k0 += 32) {
        if constexpr (MODE == 0) {
            f32x4 a0 = *(const f32x4*)(Arow + k0 + sk);
            f32x4 a1 = *(const f32x4*)(Arow + k0 + sk + 4);
            #pragma unroll
            for (int j = 0; j < 4; ++j) {
                split_bf16(a0[j], Ash[sm][sk+j],   Asl[sm][sk+j]);
                split_bf16(a1[j], Ash[sm][sk+4+j], Asl[sm][sk+4+j]);
            }
        } else {
            *(bf16x8*)&Ash[sm][sk] = *(const bf16x8*)(Ahrow + k0 + sk);
            *(bf16x8*)&Asl[sm][sk] = *(const bf16x8*)(Alrow + k0 + sk);
        }
        #pragma unroll
        for (int j = 0; j < 8; ++j) {
            float wv = W[(size_t)(k0 + sk + j) * ZDIM + gcol];
            split_bf16(wv, Bsh[sm][sk+j], Bsl[sm][sk+j]);
        }
        __syncthreads();
        #pragma unroll
        for (int mt = 0; mt < 2; ++mt) {
            #pragma unroll
            for (int nt = 0; nt < 2; ++nt) {
                bf16x8 ah = *(const bf16x8*)&Ash[wm*32 + mt*16 + l15][q*8];
                bf16x8 al = *(const bf16x8*)&Asl[wm*32 + mt*16 + l15][q*8];
                bf16x8 bh = *(const bf16x8*)&Bsh[wn*32 + nt*16 + l15][q*8];
                bf16x8 bl = *(const bf16x8*)&Bsl[wn*32 + nt*16 + l15][q*8];
                acc[mt][nt] = __builtin_amdgcn_mfma_f32_16x16x32_bf16(ah, bh, acc[mt][nt], 0, 0, 0);
                acc[mt][nt] = __builtin_amdgcn_mfma_f32_16x16x32_bf16(al, bh, acc[mt][nt], 0, 0, 0);
                acc[mt][nt] = __builtin_amdgcn_mfma_f32_16x16x32_bf16(ah, bl, acc[mt][nt], 0, 0, 0);
            }
        }
        __syncthreads();
    }
    #pragma unroll
    for (int mt = 0; mt < 2; ++mt) {
        int row = bm*64 + wm*32 + mt*16 + q*4;
        #pragma unroll
        for (int nt = 0; nt < 2; ++nt) {
            int col = bn*64 + wn*32 + nt*16 + l15;
            float bia = bias[col];
            #pragma unroll
            for (int r = 0; r < 4; ++r)
                xp[(size_t)(row + r)*ZDIM + col] = acc[mt][nt][r] + bia;
        }
    }
}

// ---------------- persistent recurrent scan: light barriers, consumer-stats ------
// grid 256 x 256. group gid=blk>>6 owns batches 8*gid..+7; block lid=blk&63 owns
// h-cols H0=lid*16..+15 for the MFMA. W in register hi/lo bf16 A-fragments.
// Per step: MFMA -> gates -> store packed (c,sg) pair (8B) -> per-wave vmcnt(0)
// (covers ONLY that store) -> raw barrier -> flag -> xp prefetch issued (flies
// through poll+staging, no drain until use) -> wave0 polls 64 flags -> raw barrier
// -> coherent csg reads (8 rows x 4 cols) -> block-local stats (wave butterfly +
// sredw LDS) -> LN+h (exp-tanh, reg gamma/beta) -> pack hi/lo into LDS.
// hseq stores are never vmem-drained in-loop (pure output). R7's __syncthreads
// drained the xp prefetch + partials + hseq every step (~2us/step of pure drain).
__global__ __launch_bounds__(256, 1) void scan_kernel(
    const float* __restrict__ Wh,      // [1024][4096] fp32 recurrent rows
    const float* __restrict__ xp,      // [cT*32][4096] fp32 x-proj (incl bias)
    const float* __restrict__ gamma,
    const float* __restrict__ beta,
    unsigned*    csg,                  // [2][32][1024][2] packed c,sg (coherent)
    unsigned*    flag,                 // [T][4][64] (zeroed)
    bf16_t*      __restrict__ hseq_hi, // [T*32][1024] or null (layer0)
    bf16_t*      __restrict__ hseq_lo,
    float*       __restrict__ outlast, // [32][1024] or null (layer1)
    bf16_t*      __restrict__ hst_hi,  // [32][1024] chunk-carry
    bf16_t*      __restrict__ hst_lo,
    float*       __restrict__ cstate,  // [32][1024]
    float*       __restrict__ mustate, // [32]
    int t0, int t1)
{
    extern __shared__ char smem[];
    bf16_t* slab_hi = (bf16_t*)smem;                       // W staging
    bf16_t* slab_lo = (bf16_t*)(smem + 64*SLAB_STRIDE*2);
    bf16_t* hl_hi   = (bf16_t*)smem;                       // [8][1040] post-staging
    bf16_t* hl_lo   = (bf16_t*)(smem + 8*HL_STRIDE*2);
    float*  sredw   = (float*)(smem + 16*HL_STRIDE*2);     // [4][8][2]

    const int gid = blockIdx.x >> 6;
    const int lid = blockIdx.x & 63;
    const int B0  = gid * 8;
    const int H0  = lid * 16;
    const int tid  = threadIdx.x;
    const int lane = tid & 63;
    const int w    = tid >> 6;
    const int q    = lane >> 4;
    const int l15  = lane & 15;

    // ---- stage recurrent W slice -> registers (hi/lo A-fragments) via LDS slabs
    bf16x8 wf_hi[32], wf_lo[32];
    {
        const int kw   = tid >> 6;
        const int strip= (tid >> 4) & 3;
        const int col  = tid & 15;
        const int gc2  = strip*1024 + H0 + col;
        const int rr_w = col*4 + strip;
        #pragma unroll
        for (int s = 0; s < 4; ++s) {
            for (int j = 0; j < 64; ++j) {
                int kk = j*4 + kw;
                float v = Wh[(size_t)(s*256 + kk)*ZDIM + gc2];
                bf16_t hi, lo; split_bf16(v, hi, lo);
                slab_hi[rr_w*SLAB_STRIDE + kk] = hi;
                slab_lo[rr_w*SLAB_STRIDE + kk] = lo;
            }
            __syncthreads();
            #pragma unroll
            for (int kbl = 0; kbl < 8; ++kbl) {
                wf_hi[s*8+kbl] = *(const bf16x8*)&slab_hi[(16*w + l15)*SLAB_STRIDE + kbl*32 + q*8];
                wf_lo[s*8+kbl] = *(const bf16x8*)&slab_lo[(16*w + l15)*SLAB_STRIDE + kbl*32 + q*8];
            }
            __syncthreads();
        }
    }

    // owner identity (MFMA C map)
    const int  bidx  = l15;
    const bool valid = bidx < 8;
    const int  batch = B0 + bidx;
    const int  hcl   = 4*w + q;
    const int  hcg   = H0 + hcl;
    const size_t xpbase = (size_t)batch * ZDIM + (size_t)H0 + hcl;
    const int hrow  = (l15 < 8) ? l15 : 7;

    // staging identity: thread owns cols cb..cb+3 for all 8 group rows
    const int cb = tid * 4;
    const f32x4 g_s = *(const f32x4*)&gamma[cb];
    const f32x4 b_s = *(const f32x4*)&beta[cb];

    float c = 0.f;
    float mu_row[8] = {0.f,0.f,0.f,0.f,0.f,0.f,0.f,0.f};
    if (t0 > 0) {
        if (valid) c = cstate[(size_t)batch*HDIM + hcg];
        #pragma unroll
        for (int r = 0; r < 8; ++r) {
            mu_row[r] = mustate[B0 + r];
            *(bf16x4*)&hl_hi[r*HL_STRIDE + cb] = *(const bf16x4*)&hst_hi[(size_t)(B0+r)*HDIM + cb];
            *(bf16x4*)&hl_lo[r*HL_STRIDE + cb] = *(const bf16x4*)&hst_lo[(size_t)(B0+r)*HDIM + cb];
        }
    }
    __syncthreads();

    // preload xp for first step
    float xpv[4] = {0.f, 0.f, 0.f, 0.f};
    if (valid) {
        const float* xpt = xp + xpbase;
        #pragma unroll
        for (int r = 0; r < 4; ++r) xpv[r] = xpt[(size_t)r * 1024];
    }

    #pragma unroll 1
    for (int t = t0; t < t1; ++t) {
        f32x4 acc_hh = {0.f,0.f,0.f,0.f}, acc_lh = acc_hh, acc_hl = acc_hh;
        if (t > 0) {
            const bf16_t* Bh = hl_hi + (size_t)hrow * HL_STRIDE + q*8;
            const bf16_t* Bl = hl_lo + (size_t)hrow * HL_STRIDE + q*8;
            #pragma unroll
            for (int kb = 0; kb < 32; ++kb) {
                bf16x8 bh = *(const bf16x8*)(Bh + kb*32);
                bf16x8 bv = *(const bf16x8*)(Bl + kb*32);
                acc_hh = __builtin_amdgcn_mfma_f32_16x16x32_bf16(wf_hi[kb], bh, acc_hh, 0, 0, 0);
                acc_lh = __builtin_amdgcn_mfma_f32_16x16x32_bf16(wf_lo[kb], bh, acc_lh, 0, 0, 0);
                acc_hl = __builtin_amdgcn_mfma_f32_16x16x32_bf16(wf_hi[kb], bv, acc_hl, 0, 0, 0);
            }
        }
        float z[4];
        #pragma unroll
        for (int r = 0; r < 4; ++r)
            z[r] = ((acc_lh[r] + acc_hl[r]) + acc_hh[r]) + xpv[r];
        float zi = fminf(fmaxf(z[0], -6.f), 3.f);
        float zf = fminf(fmaxf(z[1], -6.f), 3.f);
        float ig = __expf(zi);
        float fg = __expf(zf);
        float cand = tanh_fast(z[2]);
        float sg = 1.f / (1.f + __expf(-z[3]));
        c = fg * c + ig * cand;

        const int par = t & 1;
        // ---- publish packed (c, sg) pair: ONE 8B coherent store per owner
        if (valid) {
            u32x2 pk; pk[0] = pack_hl(c); pk[1] = pack_hl(sg);
            *(volatile u32x2*)(csg + (((size_t)par*32 + batch)*HDIM + hcg)*2) = pk;
        }
        // drain ONLY this wave's store (hseq stores from prior steps long done;
        // xp prefetch not yet issued) then raw barrier -> flag is safe
        asm volatile("s_waitcnt vmcnt(0)" ::: "memory");
        bar_raw();   // B1

        unsigned* fl = flag + ((size_t)t*4 + gid)*64;
        if (tid == 0)
            __hip_atomic_store(&fl[lid], 1u, __ATOMIC_RELAXED, __HIP_MEMORY_SCOPE_AGENT);

        // xp prefetch for t+1: issued now, flies through poll + staging + LN
        if (valid && t+1 < t1) {
            const float* xpt = xp + (size_t)(t+1 - t0) * (BATCH*ZDIM) + xpbase;
            #pragma unroll
            for (int r = 0; r < 4; ++r) xpv[r] = xpt[(size_t)r * 1024];
        }

        // ---- single rendezvous: wave0 polls all 64 block flags
        if (w == 0) {
            for (;;) {
                unsigned f = __hip_atomic_load(&fl[lane], __ATOMIC_RELAXED, __HIP_MEMORY_SCOPE_AGENT);
                if (__ballot(f != 0u) == ~0ull) break;
            }
        }
        bar_raw();   // Ba: all threads may now read published csg

        // ---- staging reads: 8 rows x 4 cols of (c,sg) pairs (coherent)
        u32x4 uu0[8], uu1[8];
        #pragma unroll
        for (int r = 0; r < 8; ++r) {
            volatile const u32x4* base =
                (volatile const u32x4*)(csg + (((size_t)par*32 + B0 + r)*HDIM + cb)*2);
            uu0[r] = base[0];
            uu1[r] = base[1];
        }

        // ---- block-local stats: per-thread partial -> 64-lane butterfly -> LDS
        float s1t[8], s2t[8];
        #pragma unroll
        for (int r = 0; r < 8; ++r) {
            float s1 = 0.f, s2 = 0.f;
            #pragma unroll
            for (int e = 0; e < 4; ++e) {
                unsigned cu = (e < 2) ? uu0[r][(e&1)*2] : uu1[r][(e&1)*2];
                float dm = unpack_hl(cu) - mu_row[r];
                s1 += dm; s2 += dm*dm;
            }
            #pragma unroll
            for (int m = 1; m < 64; m <<= 1) {
                s1 += __shfl_xor(s1, m);
                s2 += __shfl_xor(s2, m);
            }
            s1t[r] = s1; s2t[r] = s2;
        }
        if (lane == 0) {
            #pragma unroll
            for (int r = 0; r < 8; ++r) {
                sredw[(w*8 + r)*2]     = s1t[r];
                sredw[(w*8 + r)*2 + 1] = s2t[r];
            }
        }
        bar_lds();   // B2: sredw ready

        // ---- LN + h for all 8 rows (every thread, its 4 cols)
        const bool l0 = (hseq_hi != nullptr);
        const bool carry = (t == t1-1) && (t1 < T_STEPS);
        #pragma unroll
        for (int r = 0; r < 8; ++r) {
            float S1 = sredw[(0*8+r)*2] + sredw[(1*8+r)*2]
                     + sredw[(2*8+r)*2] + sredw[(3*8+r)*2];
            float S2 = sredw[(0*8+r)*2+1] + sredw[(1*8+r)*2+1]
                     + sredw[(2*8+r)*2+1] + sredw[(3*8+r)*2+1];
            float dmu = S1 * (1.f/1024.f);
            float mu  = mu_row[r] + dmu;
            float var = S2 * (1.f/1024.f) - dmu*dmu;
            float rsig = rsqrtf(var + 1e-5f);
            mu_row[r] = mu;
            bf16x4 bh, blv;
            f32x4 hv4;
            #pragma unroll
            for (int e = 0; e < 4; ++e) {
                unsigned cu = (e < 2) ? uu0[r][(e&1)*2]     : uu1[r][(e&1)*2];
                unsigned su = (e < 2) ? uu0[r][(e&1)*2 + 1] : uu1[r][(e&1)*2 + 1];
                float cv  = unpack_hl(cu);
                float sgv = unpack_hl(su);
                float ln  = (cv - mu) * rsig * g_s[e] + b_s[e];
                float h   = sgv * tanh_fast(ln);
                hv4[e] = h;
                bf16_t hi, lo; split_bf16(h, hi, lo);
                bh[e] = hi; blv[e] = lo;
            }
            *(bf16x4*)&hl_hi[r*HL_STRIDE + cb] = bh;
            *(bf16x4*)&hl_lo[r*HL_STRIDE + cb] = blv;
            if (l0 && lid == r) {
                *(bf16x4*)&hseq_hi[((size_t)t*32 + B0 + r)*HDIM + cb] = bh;
                *(bf16x4*)&hseq_lo[((size_t)t*32 + B0 + r)*HDIM + cb] = blv;
            }
            if (carry && lid == r) {
                *(bf16x4*)&hst_hi[(size_t)(B0+r)*HDIM + cb] = bh;
                *(bf16x4*)&hst_lo[(size_t)(B0+r)*HDIM + cb] = blv;
            }
            if (outlast && t == T_STEPS-1 && lid == r)
                *(f32x4*)&outlast[(size_t)(B0+r)*HDIM + cb] = hv4;
        }
        bar_lds();   // B3: hl ready for next step's MFMA (LDS only; hseq stores fly)
    }

    // chunk-carry state
    if (t1 < T_STEPS) {
        asm volatile("s_waitcnt vmcnt(0)" ::: "memory");
        if (valid) cstate[(size_t)batch*HDIM + hcg] = c;
        if (lid == 0 && tid == 0) {
            #pragma unroll
            for (int r = 0; r < 8; ++r) mustate[B0 + r] = mu_row[r];
        }
    }
}

extern "C" void kernel_launch(void* const* d_in, const int* in_sizes, int n_in,
                              void* d_out, int out_size, void* d_ws, size_t ws_size,
                              hipStream_t stream) {
    (void)in_sizes; (void)n_in;
    const float* series = (const float*)d_in[0];
    const float* W0  = (const float*)d_in[1];
    const float* b0  = (const float*)d_in[2];
    const float* g0  = (const float*)d_in[3];
    const float* be0 = (const float*)d_in[4];
    const float* W1  = (const float*)d_in[5];
    const float* b1  = (const float*)d_in[6];
    const float* g1  = (const float*)d_in[7];
    const float* be1 = (const float*)d_in[8];
    float* out = (float*)d_out;
    unsigned char* ws = (unsigned char*)d_ws;

    int cT = 0;
    const int cands[4] = {256, 128, 64, 32};
    for (int i = 0; i < 4; ++i) {
        size_t need = (size_t)cands[i]*32*ZDIM*4 + 2*SZ_HSEQ + SZ_TAIL;
        if (need <= ws_size) { cT = cands[i]; break; }
    }
    if (cT == 0) {
        (void)hipMemsetAsync(d_out, 0, (size_t)out_size * sizeof(float), stream);
        return;
    }
    const size_t sz_xp = (size_t)cT*32*ZDIM*4;
    unsigned char* p = ws;
    float*    xp      = (float*)p;    p += sz_xp;
    bf16_t*   hseq_hi = (bf16_t*)p;   p += SZ_HSEQ;
    bf16_t*   hseq_lo = (bf16_t*)p;   p += SZ_HSEQ;
    unsigned* csg     = (unsigned*)p; p += SZ_CSG;
    unsigned* flag0   = (unsigned*)p; p += SZ_FLAG;   // 2 contiguous flag arrays
    unsigned* flag1   = (unsigned*)p; p += SZ_FLAG;
    bf16_t*   hst_hi  = (bf16_t*)p;   p += SZ_HST;
    bf16_t*   hst_lo  = (bf16_t*)p;   p += SZ_HST;
    float*    cstate  = (float*)p;    p += SZ_CST;
    float*    mustate = (float*)p;

    (void)hipFuncSetAttribute((const void*)scan_kernel,
                              hipFuncAttributeMaxDynamicSharedMemorySize, SCAN_LDS);

    init_zero<<<(ZERO_WORDS + 255)/256, 256, 0, stream>>>(flag0, ZERO_WORDS);

    const int nch = T_STEPS / cT;
    const int gemm_grid = (cT*32/64) * (ZDIM/64);

    // ---- layer 0 ----
    for (int ci = 0; ci < nch; ++ci) {
        int t0 = ci*cT, t1 = t0 + cT;
        gemm_xp<256, 0><<<gemm_grid, 256, 0, stream>>>(
            series, nullptr, nullptr, W0, b0, xp, t0);
        scan_kernel<<<256, 256, SCAN_LDS, stream>>>(
            W0 + (size_t)256*ZDIM, xp, g0, be0, csg, flag0,
            hseq_hi, hseq_lo, nullptr, hst_hi, hst_lo, cstate, mustate, t0, t1);
    }
    // ---- layer 1 ----
    for (int ci = 0; ci < nch; ++ci) {
        int t0 = ci*cT, t1 = t0 + cT;
        gemm_xp<1024, 1><<<gemm_grid, 256, 0, stream>>>(
            nullptr, hseq_hi, hseq_lo, W1, b1, xp, t0);
        scan_kernel<<<256, 256, SCAN_LDS, stream>>>(
            W1 + (size_t)1024*ZDIM, xp, g1, be1, csg, flag1,
            nullptr, nullptr, out, hst_hi, hst_lo, cstate, mustate, t0, t1);
    }
}